// Round 9
// baseline (208.576 us; speedup 1.0000x reference)
//
#include <hip/hip_runtime.h>
#include <math.h>

#define D_MODEL 256
#define NHEADS 8
#define HDIM 32
#define BATCH 8
#define SEQL 4096
#define EPS 1e-6f

typedef _Float16 f16;
typedef _Float16 f16x4 __attribute__((ext_vector_type(4)));
typedef _Float16 f16x8 __attribute__((ext_vector_type(8)));
typedef float f32x4 __attribute__((ext_vector_type(4)));

__device__ __forceinline__ float elu1(float x) {
    return x > 0.f ? x + 1.f : __expf(x);
}

// ---------------------------------------------------------------------------
// prep v3: weights to fp16 in FRAGMENT-LINEAR (wfrag) layout so every MFMA
// A-fragment load is one contiguous 1 KB wave read.  Mats 0-2 (q,k,v) are
// row-permuted to head-major o' = h*32+d; mat 3 (Wm) is column-permuted.
//   wfrag index: (((ostrip*8 + kstep)*64 + lane)*8 + e)
//   o = ostrip*16 + (lane&15);  k = kstep*32 + (lane>>4)*8 + e
// ---------------------------------------------------------------------------
__global__ void prep_kernel(const float* __restrict__ Wq, const float* __restrict__ Wk,
                            const float* __restrict__ Wv, const float* __restrict__ Wm,
                            const float* __restrict__ bq, const float* __restrict__ bk,
                            const float* __restrict__ bv,
                            f16* __restrict__ w16, float* __restrict__ bperm) {
    const int bid = blockIdx.x;
    if (bid < 1024) {
        int idx = bid * 256 + threadIdx.x;
        int mat = idx >> 16;
        int r = idx & 65535;
        int e = r & 7;
        int lane = (r >> 3) & 63;
        int kstep = (r >> 9) & 7;
        int ostrip = r >> 12;
        int o = ostrip * 16 + (lane & 15);
        int k = kstep * 32 + (lane >> 4) * 8 + e;
        const float* W = (mat == 0) ? Wq : (mat == 1) ? Wk : (mat == 2) ? Wv : Wm;
        float v;
        if (mat < 3) v = W[(size_t)(((o & 31) << 3) + (o >> 5)) * 256 + k];
        else         v = W[(size_t)o * 256 + (((k & 31) << 3) + (k >> 5))];
        w16[idx] = (f16)v;
    } else {
        int t = threadIdx.x;
        bperm[0 * 256 + t] = bq[((t & 31) << 3) + (t >> 5)];
        bperm[1 * 256 + t] = bk[((t & 31) << 3) + (t >> 5)];
        bperm[2 * 256 + t] = bv[((t & 31) << 3) + (t >> 5)];
    }
}

// ---------------------------------------------------------------------------
// Stage-1 GEMM v4: stage-once structure + wfrag W loads + 4 blocks/CU
// (launch_bounds min-waves 4: LDS 33792*4=132K <= 160K, VGPR 68 <= 128).
// ---------------------------------------------------------------------------
#define XSTR 264
__global__ __launch_bounds__(256, 4) void gemm_stage1(
    const float* __restrict__ Xq, const float* __restrict__ Xk, const float* __restrict__ Xv,
    const f16* __restrict__ w16, const float* __restrict__ bperm,
    f16* __restrict__ yq, f16* __restrict__ yk, f16* __restrict__ yv) {
    __shared__ __align__(16) f16 Xs[64 * XSTR];   // 33792 B
    f16* Cb = Xs;                                  // epilogue alias (Xs dead)

    const int z = blockIdx.z;
    const int which = z >> 3;
    const int b = z & 7;
    const float* X = (which == 0) ? Xq : (which == 1) ? Xk : Xv;
    const f16* W = w16 + which * 65536;
    f16* Y = (which == 0) ? yq : (which == 1) ? yk : yv;
    const float* bp = bperm + which * 256;

    const int l0 = blockIdx.x * 64;
    const int tid = threadIdx.x;
    const int wave = tid >> 6, lane = tid & 63;
    const int ln = lane & 15, quad = lane >> 4;
    const int kq = tid & 15;    // chunk-k: k = 64c + 4*kq + r
    const int lg = tid >> 4;    // l: 4*lg + j  (lg 0..15)

    const float* Xbase = X + ((size_t)(b * D_MODEL) + 4 * kq) * SEQL + l0 + 4 * lg;

    float4 xa[4], xb[4];

#define LOADX(DST, C) do { \
        const float* xp_ = Xbase + (size_t)(64 * (C)) * SEQL; \
        DST[0] = *(const float4*)(xp_ + 0 * SEQL); \
        DST[1] = *(const float4*)(xp_ + 1 * SEQL); \
        DST[2] = *(const float4*)(xp_ + 2 * SEQL); \
        DST[3] = *(const float4*)(xp_ + 3 * SEQL); \
    } while (0)

#define STOREB(SRC, C) do { \
        f16x4 w_; \
        w_[0] = (f16)SRC[0].x; w_[1] = (f16)SRC[1].x; w_[2] = (f16)SRC[2].x; w_[3] = (f16)SRC[3].x; \
        *(f16x4*)&Xs[(4 * lg + 0) * XSTR + 64 * (C) + 4 * kq] = w_; \
        w_[0] = (f16)SRC[0].y; w_[1] = (f16)SRC[1].y; w_[2] = (f16)SRC[2].y; w_[3] = (f16)SRC[3].y; \
        *(f16x4*)&Xs[(4 * lg + 1) * XSTR + 64 * (C) + 4 * kq] = w_; \
        w_[0] = (f16)SRC[0].z; w_[1] = (f16)SRC[1].z; w_[2] = (f16)SRC[2].z; w_[3] = (f16)SRC[3].z; \
        *(f16x4*)&Xs[(4 * lg + 2) * XSTR + 64 * (C) + 4 * kq] = w_; \
        w_[0] = (f16)SRC[0].w; w_[1] = (f16)SRC[1].w; w_[2] = (f16)SRC[2].w; w_[3] = (f16)SRC[3].w; \
        *(f16x4*)&Xs[(4 * lg + 3) * XSTR + 64 * (C) + 4 * kq] = w_; \
    } while (0)

    f32x4 acc[4][4];
#pragma unroll
    for (int mf = 0; mf < 4; ++mf)
#pragma unroll
        for (int nf = 0; nf < 4; ++nf)
#pragma unroll
            for (int r = 0; r < 4; ++r) acc[mf][nf][r] = 0.f;

    // staging: 4 chunks of 64 k, 2-deep prefetch, no barriers
    LOADX(xa, 0);
    LOADX(xb, 1);
    STOREB(xa, 0);
    LOADX(xa, 2);
    STOREB(xb, 1);
    LOADX(xb, 3);
    STOREB(xa, 2);
    STOREB(xb, 3);
    __syncthreads();   // the only pre-compute barrier

    // compute: wave owns o-strip wave*64, 8 k-steps, wfrag W loads
    const f16* Wl = W + lane * 8;
    f16x8 afc[4], afn[4];
#pragma unroll
    for (int mf = 0; mf < 4; ++mf)
        afc[mf] = *(const f16x8*)(Wl + (wave * 32 + mf * 8 + 0) * 512);
#pragma unroll
    for (int s = 0; s < 8; ++s) {
        const int k0 = s * 32;
        if (s < 7) {
#pragma unroll
            for (int mf = 0; mf < 4; ++mf)
                afn[mf] = *(const f16x8*)(Wl + (wave * 32 + mf * 8 + s + 1) * 512);
        }
        f16x8 bf[4];
#pragma unroll
        for (int nf = 0; nf < 4; ++nf)
            bf[nf] = *(const f16x8*)&Xs[(nf * 16 + ln) * XSTR + k0 + quad * 8];
#pragma unroll
        for (int mf = 0; mf < 4; ++mf)
#pragma unroll
            for (int nf = 0; nf < 4; ++nf)
                acc[mf][nf] = __builtin_amdgcn_mfma_f32_16x16x32_f16(afc[mf], bf[nf], acc[mf][nf], 0, 0, 0);
#pragma unroll
        for (int mf = 0; mf < 4; ++mf) afc[mf] = afn[mf];
    }

    // epilogue: bias, bounce through Cb as [l][o], coalesced fp16 store
    float bv_[4][4];
#pragma unroll
    for (int mf = 0; mf < 4; ++mf)
#pragma unroll
        for (int r = 0; r < 4; ++r)
            bv_[mf][r] = bp[wave * 64 + mf * 16 + quad * 4 + r];
    __syncthreads();   // all Xs fragment reads complete
#pragma unroll
    for (int mf = 0; mf < 4; ++mf)
#pragma unroll
        for (int nf = 0; nf < 4; ++nf) {
            f16x4 w;
#pragma unroll
            for (int r = 0; r < 4; ++r) w[r] = (f16)(acc[mf][nf][r] + bv_[mf][r]);
            *(f16x4*)&Cb[(nf * 16 + ln) * XSTR + wave * 64 + mf * 16 + quad * 4] = w;
        }
    __syncthreads();
    {
        const int l = tid >> 2, sg = tid & 3;
        f16* yr = Y + ((size_t)(b * SEQL + l0 + l)) * 256 + sg * 64;
#pragma unroll
        for (int u = 0; u < 8; ++u)
            *(f16x8*)(yr + u * 8) = *(const f16x8*)&Cb[l * XSTR + sg * 64 + u * 8];
    }
#undef LOADX
#undef STOREB
}

// ---------------------------------------------------------------------------
// kv_mfma: per (lsplit, b, h) block, KVpart[ls][bh][qd][kd] =
//   sum_{l in split} v'[l][qd] * elu1(k'[l][kd]);  ksum via augmented A-row
//   of ones (vT row 32).  16 splits of 256 l -> 1024 blocks (CU-matched).
// ---------------------------------------------------------------------------
#define KVLP 66
#define NSPLIT 16
__global__ __launch_bounds__(256) void kv_mfma(
    const f16* __restrict__ kp, const f16* __restrict__ vp,
    float* __restrict__ KVpart, float* __restrict__ ksum_part) {
    __shared__ __align__(16) f16 kT[32 * KVLP];   // [kd][l]  (elu applied)
    __shared__ __align__(16) f16 vT[48 * KVLP];   // [qd][l]; rows 32..47: ones-row aug
    const int ls = blockIdx.x;    // 0..15 (l split of 256)
    const int bh = blockIdx.y;    // 0..63
    const int b = bh >> 3, h = bh & 7;
    const int t = threadIdx.x;
    const int wave = t >> 6, lane = t & 63;
    const int ln = lane & 15, quad = lane >> 4;
    const int lrow = t >> 2, seg = t & 3;

    {
        const int rr = 32 + (t >> 4), c0 = (t & 15) * 4;
        f16x4 w;
        const f16 one = (f16)1.f, zero = (f16)0.f;
        w[0] = w[1] = w[2] = w[3] = (rr == 32) ? one : zero;
        *(f16x4*)&vT[rr * KVLP + c0] = w;
    }

    const int tiP = wave >> 1, tjP = wave & 1;
    f32x4 accP, accS;
#pragma unroll
    for (int r = 0; r < 4; ++r) { accP[r] = 0.f; accS[r] = 0.f; }

    for (int ch = 0; ch < 4; ++ch) {
        __syncthreads();
        const size_t goff = ((size_t)(b * SEQL + ls * 256 + ch * 64 + lrow)) * 256 + h * 32 + seg * 8;
        f16x8 k8 = *(const f16x8*)(kp + goff);
        f16x8 v8 = *(const f16x8*)(vp + goff);
#pragma unroll
        for (int j = 0; j < 8; ++j) {
            kT[(seg * 8 + j) * KVLP + lrow] = (f16)elu1((float)k8[j]);
            vT[(seg * 8 + j) * KVLP + lrow] = v8[j];
        }
        __syncthreads();
#pragma unroll
        for (int ks = 0; ks < 2; ++ks) {
            const int kc = ks * 32 + quad * 8;
            f16x8 bP = *(const f16x8*)&kT[(tjP * 16 + ln) * KVLP + kc];
            f16x8 aP = *(const f16x8*)&vT[(tiP * 16 + ln) * KVLP + kc];
            accP = __builtin_amdgcn_mfma_f32_16x16x32_f16(aP, bP, accP, 0, 0, 0);
            if (wave < 2) {
                f16x8 aS = *(const f16x8*)&vT[(32 + ln) * KVLP + kc];
                accS = __builtin_amdgcn_mfma_f32_16x16x32_f16(aS, bP, accS, 0, 0, 0);
            }
        }
    }

    float* KVp = KVpart + ((size_t)ls * 64 + bh) * 1024;
#pragma unroll
    for (int r = 0; r < 4; ++r)
        KVp[(tiP * 16 + quad * 4 + r) * 32 + tjP * 16 + ln] = accP[r];
    if (wave < 2 && quad == 0)
        ksum_part[((size_t)ls * 64 + bh) * 32 + tjP * 16 + ln] = accS[0];
}

// ---------------------------------------------------------------------------
// kv_reduce: sum the 16 lsplit partials -> final KV [bh][qd][kd], ksum [bh][kd]
// ---------------------------------------------------------------------------
__global__ __launch_bounds__(256) void kv_reduce(
    const float* __restrict__ KVpart, const float* __restrict__ ksum_part,
    float* __restrict__ KVfin, float* __restrict__ ksum_f) {
    const int bh = blockIdx.x;
    const int t = threadIdx.x;
    const float* src = KVpart + (size_t)bh * 1024 + t * 4;
    float ax = 0.f, ay = 0.f, az = 0.f, aw = 0.f;
#pragma unroll
    for (int s = 0; s < NSPLIT; ++s) {
        float4 p = *(const float4*)(src + (size_t)s * 65536);
        ax += p.x; ay += p.y; az += p.z; aw += p.w;
    }
    float4 o; o.x = ax; o.y = ay; o.z = az; o.w = aw;
    *(float4*)(KVfin + (size_t)bh * 1024 + t * 4) = o;
    if (t < 32) {
        float ss = 0.f;
#pragma unroll
        for (int s = 0; s < NSPLIT; ++s)
            ss += ksum_part[((size_t)s * 64 + bh) * 32 + t];
        ksum_f[bh * 32 + t] = ss;
    }
}

// ---------------------------------------------------------------------------
// Fused attention + output projection.  Coalesced lane-linear xs staging;
// wfrag Wm; output epilogue bounced through f32 LDS tile [128][66]
// (aliases dead xs) -> float4 row stores (4 rows x 256 B per wave-instr).
// ---------------------------------------------------------------------------
__global__ __launch_bounds__(256) void attn_out_kernel(
    const f16* __restrict__ qp, const float* __restrict__ KV,
    const float* __restrict__ ksum, const f16* __restrict__ wm16,
    const float* __restrict__ bm, float* __restrict__ out) {
    __shared__ __align__(16) f16 xs[64 * 264];        // 33792 B
    __shared__ __align__(16) f16 Baug[8 * 48 * 40];   // 30720 B
    __shared__ float dens[8][64];                     // 2048 B
    const int b = blockIdx.y;
    const int l0 = blockIdx.x * 64;
    const int t = threadIdx.x;
    const int wave = t >> 6, lane = t & 63;
    const int ln = lane & 15, quad = lane >> 4;

    {
        const int h = t >> 5, qd = t & 31;
        const float* kvp = KV + ((size_t)(b * NHEADS + h) * HDIM + qd) * HDIM;
        f16* dst = &Baug[(h * 48 + qd) * 40];
#pragma unroll
        for (int i = 0; i < 32; i += 4) {
            float4 a = *(const float4*)(kvp + i);
            f16x4 w4;
            w4[0] = (f16)a.x; w4[1] = (f16)a.y; w4[2] = (f16)a.z; w4[3] = (f16)a.w;
            *(f16x4*)(dst + i) = w4;
        }
        Baug[(h * 48 + 32) * 40 + qd] = (f16)ksum[(size_t)(b * NHEADS + h) * HDIM + qd];
    }
    {
        // lane-linear coalesced qp staging
        const int rbase = t >> 5, ch = (t & 31) * 8;
        const f16* qr = qp + ((size_t)(b * SEQL + l0 + rbase)) * 256 + ch;
        f16* dst = &xs[rbase * 264 + ch];
#pragma unroll
        for (int p = 0; p < 8; ++p) {
            f16x8 v = *(const f16x8*)(qr + (size_t)(p * 8) * 256);
            f16x8 w;
#pragma unroll
            for (int j = 0; j < 8; ++j) w[j] = (f16)elu1((float)v[j]);
            *(f16x8*)(dst + p * 8 * 264) = w;
        }
    }
    __syncthreads();
#pragma unroll
    for (int hh = 0; hh < 2; ++hh) {
        const int h = wave * 2 + hh;
        f16x8 a_s[4], b_s[3];
#pragma unroll
        for (int mf = 0; mf < 4; ++mf)
            a_s[mf] = *(const f16x8*)&xs[(mf * 16 + ln) * 264 + h * 32 + quad * 8];
#pragma unroll
        for (int nf = 0; nf < 3; ++nf)
            b_s[nf] = *(const f16x8*)&Baug[(h * 48 + nf * 16 + ln) * 40 + quad * 8];
        f32x4 C[4][3];
#pragma unroll
        for (int mf = 0; mf < 4; ++mf)
#pragma unroll
            for (int nf = 0; nf < 3; ++nf) {
#pragma unroll
                for (int r = 0; r < 4; ++r) C[mf][nf][r] = 0.f;
                C[mf][nf] = __builtin_amdgcn_mfma_f32_16x16x32_f16(a_s[mf], b_s[nf], C[mf][nf], 0, 0, 0);
            }
        if (ln == 0) {
#pragma unroll
            for (int mf = 0; mf < 4; ++mf)
#pragma unroll
                for (int r = 0; r < 4; ++r)
                    dens[h][mf * 16 + quad * 4 + r] = C[mf][2][r];
        }
        __syncthreads();
#pragma unroll
        for (int mf = 0; mf < 4; ++mf)
#pragma unroll
            for (int r = 0; r < 4; ++r) {
                const int l = mf * 16 + quad * 4 + r;
                const float rd = __builtin_amdgcn_rcpf(dens[h][l] + EPS);
#pragma unroll
                for (int nf = 0; nf < 2; ++nf)
                    xs[l * 264 + h * 32 + nf * 16 + ln] = (f16)(C[mf][nf][r] * rd);
            }
        __syncthreads();
    }
    // phase2: main GEMM, A = Wm via wfrag (coalesced), B = xs
    f32x4 acc[4][4];
#pragma unroll
    for (int mf = 0; mf < 4; ++mf)
#pragma unroll
        for (int nf = 0; nf < 4; ++nf)
#pragma unroll
            for (int r = 0; r < 4; ++r) acc[mf][nf][r] = 0.f;
    const f16* Wl = wm16 + lane * 8;
    f16x8 afc[4], afn[4];
#pragma unroll
    for (int mf = 0; mf < 4; ++mf)
        afc[mf] = *(const f16x8*)(Wl + (wave * 32 + mf * 8 + 0) * 512);
#pragma unroll
    for (int it = 0; it < 8; ++it) {
        const int k0 = it * 32;
        if (it < 7) {
#pragma unroll
            for (int mf = 0; mf < 4; ++mf)
                afn[mf] = *(const f16x8*)(Wl + (wave * 32 + mf * 8 + it + 1) * 512);
        }
        f16x8 bf[4];
#pragma unroll
        for (int nf = 0; nf < 4; ++nf)
            bf[nf] = *(const f16x8*)&xs[(nf * 16 + ln) * 264 + k0 + quad * 8];
#pragma unroll
        for (int mf = 0; mf < 4; ++mf)
#pragma unroll
            for (int nf = 0; nf < 4; ++nf)
                acc[mf][nf] = __builtin_amdgcn_mfma_f32_16x16x32_f16(afc[mf], bf[nf], acc[mf][nf], 0, 0, 0);
#pragma unroll
        for (int mf = 0; mf < 4; ++mf) afc[mf] = afn[mf];
    }
    // epilogue: bias, bounce through f32 LDS [128][66] (aliases xs),
    // then coalesced float4 row stores.
    float* Of = (float*)xs;
    __syncthreads();   // all xs fragment reads complete
#pragma unroll
    for (int p = 0; p < 2; ++p) {
        if ((wave >> 1) == p) {
            const int rb = (wave & 1) * 64;
#pragma unroll
            for (int mf = 0; mf < 4; ++mf)
#pragma unroll
                for (int r = 0; r < 4; ++r) {
                    const int o = wave * 64 + mf * 16 + quad * 4 + r;
                    const float bb = bm[o];
                    const int row = rb + mf * 16 + quad * 4 + r;
#pragma unroll
                    for (int nf = 0; nf < 4; ++nf)
                        Of[row * 66 + nf * 16 + ln] = acc[mf][nf][r] + bb;
                }
        }
        __syncthreads();
        {
            const int rw = t >> 4, lc = (t & 15) * 4;
#pragma unroll
            for (int rnd = 0; rnd < 8; ++rnd) {
                const int row = rnd * 16 + rw;
                float4 v4 = *(const float4*)&Of[row * 66 + lc];
                *(float4*)(out + ((size_t)(b * D_MODEL + p * 128 + row)) * SEQL + l0 + lc) = v4;
            }
        }
        __syncthreads();
    }
}

// ---------------------------------------------------------------------------
extern "C" void kernel_launch(void* const* d_in, const int* in_sizes, int n_in,
                              void* d_out, int out_size, void* d_ws, size_t ws_size,
                              hipStream_t stream) {
    const float* query = (const float*)d_in[0];
    const float* key_  = (const float*)d_in[1];
    const float* value = (const float*)d_in[2];
    const float* Wq = (const float*)d_in[3];
    const float* bq = (const float*)d_in[4];
    const float* Wk = (const float*)d_in[5];
    const float* bk = (const float*)d_in[6];
    const float* Wv = (const float*)d_in[7];
    const float* bv = (const float*)d_in[8];
    const float* Wm = (const float*)d_in[9];
    const float* bm = (const float*)d_in[10];

    char* w = (char*)d_ws;
    f16*   w16    = (f16*)w;                        // 524288 B
    float* bperm  = (float*)(w + 524288);           // 3072 B
    float* KVpart = (float*)(w + 528384);           // 16*64*1024*4 = 4194304 B
    float* ksum_p = (float*)(w + 4722688);          // 16*64*32*4 = 131072 B
    float* KVfin  = (float*)(w + 4853760);          // 262144 B
    float* ksum_f = (float*)(w + 5115904);          // 8192 B
    f16*   qp     = (f16*)(w + 5124096);            // 16.7 MB each
    f16*   kp     = qp + (size_t)BATCH * SEQL * 256;
    f16*   vp     = kp + (size_t)BATCH * SEQL * 256;

    prep_kernel<<<1025, 256, 0, stream>>>(Wq, Wk, Wv, Wm, bq, bk, bv, w16, bperm);

    gemm_stage1<<<dim3(SEQL / 64, 1, 24), 256, 0, stream>>>(
        query, key_, value, w16, bperm, qp, kp, vp);

    kv_mfma<<<dim3(NSPLIT, BATCH * NHEADS), 256, 0, stream>>>(kp, vp, KVpart, ksum_p);

    kv_reduce<<<dim3(BATCH * NHEADS), 256, 0, stream>>>(KVpart, ksum_p, KVfin, ksum_f);

    attn_out_kernel<<<dim3(SEQL / 64, BATCH), 256, 0, stream>>>(
        qp, KVfin, ksum_f, w16 + 3 * 65536, bm, (float*)d_out);
}

// Round 10
// 193.646 us; speedup vs baseline: 1.0771x; 1.0771x over previous
//
#include <hip/hip_runtime.h>
#include <math.h>

#define D_MODEL 256
#define NHEADS 8
#define HDIM 32
#define BATCH 8
#define SEQL 4096
#define EPS 1e-6f

typedef _Float16 f16;
typedef _Float16 f16x4 __attribute__((ext_vector_type(4)));
typedef _Float16 f16x8 __attribute__((ext_vector_type(8)));
typedef float f32x4 __attribute__((ext_vector_type(4)));

__device__ __forceinline__ float elu1(float x) {
    return x > 0.f ? x + 1.f : __expf(x);
}

// ---------------------------------------------------------------------------
// prep v3: weights to fp16 in FRAGMENT-LINEAR (wfrag) layout so every MFMA
// A-fragment load is one contiguous 1 KB wave read.  Mats 0-2 (q,k,v) are
// row-permuted to head-major o' = h*32+d; mat 3 (Wm) is column-permuted.
//   wfrag index: (((ostrip*8 + kstep)*64 + lane)*8 + e)
//   o = ostrip*16 + (lane&15);  k = kstep*32 + (lane>>4)*8 + e
// ---------------------------------------------------------------------------
__global__ void prep_kernel(const float* __restrict__ Wq, const float* __restrict__ Wk,
                            const float* __restrict__ Wv, const float* __restrict__ Wm,
                            const float* __restrict__ bq, const float* __restrict__ bk,
                            const float* __restrict__ bv,
                            f16* __restrict__ w16, float* __restrict__ bperm) {
    const int bid = blockIdx.x;
    if (bid < 1024) {
        int idx = bid * 256 + threadIdx.x;
        int mat = idx >> 16;
        int r = idx & 65535;
        int e = r & 7;
        int lane = (r >> 3) & 63;
        int kstep = (r >> 9) & 7;
        int ostrip = r >> 12;
        int o = ostrip * 16 + (lane & 15);
        int k = kstep * 32 + (lane >> 4) * 8 + e;
        const float* W = (mat == 0) ? Wq : (mat == 1) ? Wk : (mat == 2) ? Wv : Wm;
        float v;
        if (mat < 3) v = W[(size_t)(((o & 31) << 3) + (o >> 5)) * 256 + k];
        else         v = W[(size_t)o * 256 + (((k & 31) << 3) + (k >> 5))];
        w16[idx] = (f16)v;
    } else {
        int t = threadIdx.x;
        bperm[0 * 256 + t] = bq[((t & 31) << 3) + (t >> 5)];
        bperm[1 * 256 + t] = bk[((t & 31) << 3) + (t >> 5)];
        bperm[2 * 256 + t] = bv[((t & 31) << 3) + (t >> 5)];
    }
}

// ---------------------------------------------------------------------------
// Stage-1 GEMM v5: stage-once structure + wfrag W + FULL-LINE X loads and
// Y stores.  Lane-role swap (kq=t>>4, lg=t&15) makes each X wave-instruction
// read 4 rows x 256 B (8 full 128 B lines, was 16x64 B segments); Y-store
// remap gives 8 rows x 128 B per instruction (was 16x64 B).  bounds back to 3
// (4 blocks/CU regressed: L2 pressure, FETCH 51->55 MB).
// ---------------------------------------------------------------------------
#define XSTR 264
__global__ __launch_bounds__(256, 3) void gemm_stage1(
    const float* __restrict__ Xq, const float* __restrict__ Xk, const float* __restrict__ Xv,
    const f16* __restrict__ w16, const float* __restrict__ bperm,
    f16* __restrict__ yq, f16* __restrict__ yk, f16* __restrict__ yv) {
    __shared__ __align__(16) f16 Xs[64 * XSTR];   // 33792 B
    f16* Cb = Xs;                                  // epilogue alias (Xs dead)

    const int z = blockIdx.z;
    const int which = z >> 3;
    const int b = z & 7;
    const float* X = (which == 0) ? Xq : (which == 1) ? Xk : Xv;
    const f16* W = w16 + which * 65536;
    f16* Y = (which == 0) ? yq : (which == 1) ? yk : yv;
    const float* bp = bperm + which * 256;

    const int l0 = blockIdx.x * 64;
    const int tid = threadIdx.x;
    const int wave = tid >> 6, lane = tid & 63;
    const int ln = lane & 15, quad = lane >> 4;
    const int kq = tid >> 4;    // chunk-k: k = 64c + 4*kq + r  (4 rows/wave-instr)
    const int lg = tid & 15;    // l: 4*lg + j  (16 lanes x 16B = 256B runs)

    const float* Xbase = X + ((size_t)(b * D_MODEL) + 4 * kq) * SEQL + l0 + 4 * lg;

    float4 xa[4], xb[4];

#define LOADX(DST, C) do { \
        const float* xp_ = Xbase + (size_t)(64 * (C)) * SEQL; \
        DST[0] = *(const float4*)(xp_ + 0 * SEQL); \
        DST[1] = *(const float4*)(xp_ + 1 * SEQL); \
        DST[2] = *(const float4*)(xp_ + 2 * SEQL); \
        DST[3] = *(const float4*)(xp_ + 3 * SEQL); \
    } while (0)

#define STOREB(SRC, C) do { \
        f16x4 w_; \
        w_[0] = (f16)SRC[0].x; w_[1] = (f16)SRC[1].x; w_[2] = (f16)SRC[2].x; w_[3] = (f16)SRC[3].x; \
        *(f16x4*)&Xs[(4 * lg + 0) * XSTR + 64 * (C) + 4 * kq] = w_; \
        w_[0] = (f16)SRC[0].y; w_[1] = (f16)SRC[1].y; w_[2] = (f16)SRC[2].y; w_[3] = (f16)SRC[3].y; \
        *(f16x4*)&Xs[(4 * lg + 1) * XSTR + 64 * (C) + 4 * kq] = w_; \
        w_[0] = (f16)SRC[0].z; w_[1] = (f16)SRC[1].z; w_[2] = (f16)SRC[2].z; w_[3] = (f16)SRC[3].z; \
        *(f16x4*)&Xs[(4 * lg + 2) * XSTR + 64 * (C) + 4 * kq] = w_; \
        w_[0] = (f16)SRC[0].w; w_[1] = (f16)SRC[1].w; w_[2] = (f16)SRC[2].w; w_[3] = (f16)SRC[3].w; \
        *(f16x4*)&Xs[(4 * lg + 3) * XSTR + 64 * (C) + 4 * kq] = w_; \
    } while (0)

    f32x4 acc[4][4];
#pragma unroll
    for (int mf = 0; mf < 4; ++mf)
#pragma unroll
        for (int nf = 0; nf < 4; ++nf)
#pragma unroll
            for (int r = 0; r < 4; ++r) acc[mf][nf][r] = 0.f;

    // staging: 4 chunks of 64 k, 2-deep prefetch, no barriers
    LOADX(xa, 0);
    LOADX(xb, 1);
    STOREB(xa, 0);
    LOADX(xa, 2);
    STOREB(xb, 1);
    LOADX(xb, 3);
    STOREB(xa, 2);
    STOREB(xb, 3);
    __syncthreads();   // the only pre-compute barrier

    // compute: wave owns o-strip wave*64, 8 k-steps, wfrag W loads
    const f16* Wl = W + lane * 8;
    f16x8 afc[4], afn[4];
#pragma unroll
    for (int mf = 0; mf < 4; ++mf)
        afc[mf] = *(const f16x8*)(Wl + (wave * 32 + mf * 8 + 0) * 512);
#pragma unroll
    for (int s = 0; s < 8; ++s) {
        const int k0 = s * 32;
        if (s < 7) {
#pragma unroll
            for (int mf = 0; mf < 4; ++mf)
                afn[mf] = *(const f16x8*)(Wl + (wave * 32 + mf * 8 + s + 1) * 512);
        }
        f16x8 bf[4];
#pragma unroll
        for (int nf = 0; nf < 4; ++nf)
            bf[nf] = *(const f16x8*)&Xs[(nf * 16 + ln) * XSTR + k0 + quad * 8];
#pragma unroll
        for (int mf = 0; mf < 4; ++mf)
#pragma unroll
            for (int nf = 0; nf < 4; ++nf)
                acc[mf][nf] = __builtin_amdgcn_mfma_f32_16x16x32_f16(afc[mf], bf[nf], acc[mf][nf], 0, 0, 0);
#pragma unroll
        for (int mf = 0; mf < 4; ++mf) afc[mf] = afn[mf];
    }

    // epilogue: bias, bounce through Cb as [l][o], full-line fp16 stores
    float bv_[4][4];
#pragma unroll
    for (int mf = 0; mf < 4; ++mf)
#pragma unroll
        for (int r = 0; r < 4; ++r)
            bv_[mf][r] = bp[wave * 64 + mf * 16 + quad * 4 + r];
    __syncthreads();   // all Xs fragment reads complete
#pragma unroll
    for (int mf = 0; mf < 4; ++mf)
#pragma unroll
        for (int nf = 0; nf < 4; ++nf) {
            f16x4 w;
#pragma unroll
            for (int r = 0; r < 4; ++r) w[r] = (f16)(acc[mf][nf][r] + bv_[mf][r]);
            *(f16x4*)&Cb[(nf * 16 + ln) * XSTR + wave * 64 + mf * 16 + quad * 4] = w;
        }
    __syncthreads();
    {
        const int rw = tid >> 3, sg = tid & 7;   // 8 rows x 128B per wave-instr
#pragma unroll
        for (int u = 0; u < 8; ++u) {
            const int row = (u & 1) * 32 + rw;
            const int col = (u >> 1) * 64 + sg * 8;
            *(f16x8*)(Y + ((size_t)(b * SEQL + l0 + row)) * 256 + col) =
                *(const f16x8*)&Cb[row * XSTR + col];
        }
    }
#undef LOADX
#undef STOREB
}

// ---------------------------------------------------------------------------
// kv_mfma: per (lsplit, b, h) block, KVpart[ls][bh][qd][kd] =
//   sum_{l in split} v'[l][qd] * elu1(k'[l][kd]);  ksum via augmented A-row
//   of ones (vT row 32).  16 splits of 256 l -> 1024 blocks (CU-matched).
// ---------------------------------------------------------------------------
#define KVLP 66
#define NSPLIT 16
__global__ __launch_bounds__(256) void kv_mfma(
    const f16* __restrict__ kp, const f16* __restrict__ vp,
    float* __restrict__ KVpart, float* __restrict__ ksum_part) {
    __shared__ __align__(16) f16 kT[32 * KVLP];   // [kd][l]  (elu applied)
    __shared__ __align__(16) f16 vT[48 * KVLP];   // [qd][l]; rows 32..47: ones-row aug
    const int ls = blockIdx.x;    // 0..15 (l split of 256)
    const int bh = blockIdx.y;    // 0..63
    const int b = bh >> 3, h = bh & 7;
    const int t = threadIdx.x;
    const int wave = t >> 6, lane = t & 63;
    const int ln = lane & 15, quad = lane >> 4;
    const int lrow = t >> 2, seg = t & 3;

    {
        const int rr = 32 + (t >> 4), c0 = (t & 15) * 4;
        f16x4 w;
        const f16 one = (f16)1.f, zero = (f16)0.f;
        w[0] = w[1] = w[2] = w[3] = (rr == 32) ? one : zero;
        *(f16x4*)&vT[rr * KVLP + c0] = w;
    }

    const int tiP = wave >> 1, tjP = wave & 1;
    f32x4 accP, accS;
#pragma unroll
    for (int r = 0; r < 4; ++r) { accP[r] = 0.f; accS[r] = 0.f; }

    for (int ch = 0; ch < 4; ++ch) {
        __syncthreads();
        const size_t goff = ((size_t)(b * SEQL + ls * 256 + ch * 64 + lrow)) * 256 + h * 32 + seg * 8;
        f16x8 k8 = *(const f16x8*)(kp + goff);
        f16x8 v8 = *(const f16x8*)(vp + goff);
#pragma unroll
        for (int j = 0; j < 8; ++j) {
            kT[(seg * 8 + j) * KVLP + lrow] = (f16)elu1((float)k8[j]);
            vT[(seg * 8 + j) * KVLP + lrow] = v8[j];
        }
        __syncthreads();
#pragma unroll
        for (int ks = 0; ks < 2; ++ks) {
            const int kc = ks * 32 + quad * 8;
            f16x8 bP = *(const f16x8*)&kT[(tjP * 16 + ln) * KVLP + kc];
            f16x8 aP = *(const f16x8*)&vT[(tiP * 16 + ln) * KVLP + kc];
            accP = __builtin_amdgcn_mfma_f32_16x16x32_f16(aP, bP, accP, 0, 0, 0);
            if (wave < 2) {
                f16x8 aS = *(const f16x8*)&vT[(32 + ln) * KVLP + kc];
                accS = __builtin_amdgcn_mfma_f32_16x16x32_f16(aS, bP, accS, 0, 0, 0);
            }
        }
    }

    float* KVp = KVpart + ((size_t)ls * 64 + bh) * 1024;
#pragma unroll
    for (int r = 0; r < 4; ++r)
        KVp[(tiP * 16 + quad * 4 + r) * 32 + tjP * 16 + ln] = accP[r];
    if (wave < 2 && quad == 0)
        ksum_part[((size_t)ls * 64 + bh) * 32 + tjP * 16 + ln] = accS[0];
}

// ---------------------------------------------------------------------------
// kv_reduce: sum the 16 lsplit partials -> final KV [bh][qd][kd], ksum [bh][kd]
// ---------------------------------------------------------------------------
__global__ __launch_bounds__(256) void kv_reduce(
    const float* __restrict__ KVpart, const float* __restrict__ ksum_part,
    float* __restrict__ KVfin, float* __restrict__ ksum_f) {
    const int bh = blockIdx.x;
    const int t = threadIdx.x;
    const float* src = KVpart + (size_t)bh * 1024 + t * 4;
    float ax = 0.f, ay = 0.f, az = 0.f, aw = 0.f;
#pragma unroll
    for (int s = 0; s < NSPLIT; ++s) {
        float4 p = *(const float4*)(src + (size_t)s * 65536);
        ax += p.x; ay += p.y; az += p.z; aw += p.w;
    }
    float4 o; o.x = ax; o.y = ay; o.z = az; o.w = aw;
    *(float4*)(KVfin + (size_t)bh * 1024 + t * 4) = o;
    if (t < 32) {
        float ss = 0.f;
#pragma unroll
        for (int s = 0; s < NSPLIT; ++s)
            ss += ksum_part[((size_t)s * 64 + bh) * 32 + t];
        ksum_f[bh * 32 + t] = ss;
    }
}

// ---------------------------------------------------------------------------
// Fused attention + output projection.  Coalesced lane-linear xs staging;
// wfrag Wm; output epilogue bounced through f32 LDS tile [128][66]
// (aliases dead xs) -> float4 row stores (4 rows x 256 B per wave-instr).
// ---------------------------------------------------------------------------
__global__ __launch_bounds__(256) void attn_out_kernel(
    const f16* __restrict__ qp, const float* __restrict__ KV,
    const float* __restrict__ ksum, const f16* __restrict__ wm16,
    const float* __restrict__ bm, float* __restrict__ out) {
    __shared__ __align__(16) f16 xs[64 * 264];        // 33792 B
    __shared__ __align__(16) f16 Baug[8 * 48 * 40];   // 30720 B
    __shared__ float dens[8][64];                     // 2048 B
    const int b = blockIdx.y;
    const int l0 = blockIdx.x * 64;
    const int t = threadIdx.x;
    const int wave = t >> 6, lane = t & 63;
    const int ln = lane & 15, quad = lane >> 4;

    {
        const int h = t >> 5, qd = t & 31;
        const float* kvp = KV + ((size_t)(b * NHEADS + h) * HDIM + qd) * HDIM;
        f16* dst = &Baug[(h * 48 + qd) * 40];
#pragma unroll
        for (int i = 0; i < 32; i += 4) {
            float4 a = *(const float4*)(kvp + i);
            f16x4 w4;
            w4[0] = (f16)a.x; w4[1] = (f16)a.y; w4[2] = (f16)a.z; w4[3] = (f16)a.w;
            *(f16x4*)(dst + i) = w4;
        }
        Baug[(h * 48 + 32) * 40 + qd] = (f16)ksum[(size_t)(b * NHEADS + h) * HDIM + qd];
    }
    {
        // lane-linear coalesced qp staging
        const int rbase = t >> 5, ch = (t & 31) * 8;
        const f16* qr = qp + ((size_t)(b * SEQL + l0 + rbase)) * 256 + ch;
        f16* dst = &xs[rbase * 264 + ch];
#pragma unroll
        for (int p = 0; p < 8; ++p) {
            f16x8 v = *(const f16x8*)(qr + (size_t)(p * 8) * 256);
            f16x8 w;
#pragma unroll
            for (int j = 0; j < 8; ++j) w[j] = (f16)elu1((float)v[j]);
            *(f16x8*)(dst + p * 8 * 264) = w;
        }
    }
    __syncthreads();
#pragma unroll
    for (int hh = 0; hh < 2; ++hh) {
        const int h = wave * 2 + hh;
        f16x8 a_s[4], b_s[3];
#pragma unroll
        for (int mf = 0; mf < 4; ++mf)
            a_s[mf] = *(const f16x8*)&xs[(mf * 16 + ln) * 264 + h * 32 + quad * 8];
#pragma unroll
        for (int nf = 0; nf < 3; ++nf)
            b_s[nf] = *(const f16x8*)&Baug[(h * 48 + nf * 16 + ln) * 40 + quad * 8];
        f32x4 C[4][3];
#pragma unroll
        for (int mf = 0; mf < 4; ++mf)
#pragma unroll
            for (int nf = 0; nf < 3; ++nf) {
#pragma unroll
                for (int r = 0; r < 4; ++r) C[mf][nf][r] = 0.f;
                C[mf][nf] = __builtin_amdgcn_mfma_f32_16x16x32_f16(a_s[mf], b_s[nf], C[mf][nf], 0, 0, 0);
            }
        if (ln == 0) {
#pragma unroll
            for (int mf = 0; mf < 4; ++mf)
#pragma unroll
                for (int r = 0; r < 4; ++r)
                    dens[h][mf * 16 + quad * 4 + r] = C[mf][2][r];
        }
        __syncthreads();
#pragma unroll
        for (int mf = 0; mf < 4; ++mf)
#pragma unroll
            for (int r = 0; r < 4; ++r) {
                const int l = mf * 16 + quad * 4 + r;
                const float rd = __builtin_amdgcn_rcpf(dens[h][l] + EPS);
#pragma unroll
                for (int nf = 0; nf < 2; ++nf)
                    xs[l * 264 + h * 32 + nf * 16 + ln] = (f16)(C[mf][nf][r] * rd);
            }
        __syncthreads();
    }
    // phase2: main GEMM, A = Wm via wfrag (coalesced), B = xs
    f32x4 acc[4][4];
#pragma unroll
    for (int mf = 0; mf < 4; ++mf)
#pragma unroll
        for (int nf = 0; nf < 4; ++nf)
#pragma unroll
            for (int r = 0; r < 4; ++r) acc[mf][nf][r] = 0.f;
    const f16* Wl = wm16 + lane * 8;
    f16x8 afc[4], afn[4];
#pragma unroll
    for (int mf = 0; mf < 4; ++mf)
        afc[mf] = *(const f16x8*)(Wl + (wave * 32 + mf * 8 + 0) * 512);
#pragma unroll
    for (int it = 0; it < 8; ++it) {
        const int k0 = it * 32;
        if (it < 7) {
#pragma unroll
            for (int mf = 0; mf < 4; ++mf)
                afn[mf] = *(const f16x8*)(Wl + (wave * 32 + mf * 8 + it + 1) * 512);
        }
        f16x8 bf[4];
#pragma unroll
        for (int nf = 0; nf < 4; ++nf)
            bf[nf] = *(const f16x8*)&xs[(nf * 16 + ln) * 264 + k0 + quad * 8];
#pragma unroll
        for (int mf = 0; mf < 4; ++mf)
#pragma unroll
            for (int nf = 0; nf < 4; ++nf)
                acc[mf][nf] = __builtin_amdgcn_mfma_f32_16x16x32_f16(afc[mf], bf[nf], acc[mf][nf], 0, 0, 0);
#pragma unroll
        for (int mf = 0; mf < 4; ++mf) afc[mf] = afn[mf];
    }
    // epilogue: bias, bounce through f32 LDS [128][66] (aliases xs),
    // then coalesced float4 row stores.
    float* Of = (float*)xs;
    __syncthreads();   // all xs fragment reads complete
#pragma unroll
    for (int p = 0; p < 2; ++p) {
        if ((wave >> 1) == p) {
            const int rb = (wave & 1) * 64;
#pragma unroll
            for (int mf = 0; mf < 4; ++mf)
#pragma unroll
                for (int r = 0; r < 4; ++r) {
                    const int o = wave * 64 + mf * 16 + quad * 4 + r;
                    const float bb = bm[o];
                    const int row = rb + mf * 16 + quad * 4 + r;
#pragma unroll
                    for (int nf = 0; nf < 4; ++nf)
                        Of[row * 66 + nf * 16 + ln] = acc[mf][nf][r] + bb;
                }
        }
        __syncthreads();
        {
            const int rw = t >> 4, lc = (t & 15) * 4;
#pragma unroll
            for (int rnd = 0; rnd < 8; ++rnd) {
                const int row = rnd * 16 + rw;
                float4 v4 = *(const float4*)&Of[row * 66 + lc];
                *(float4*)(out + ((size_t)(b * D_MODEL + p * 128 + row)) * SEQL + l0 + lc) = v4;
            }
        }
        __syncthreads();
    }
}

// ---------------------------------------------------------------------------
extern "C" void kernel_launch(void* const* d_in, const int* in_sizes, int n_in,
                              void* d_out, int out_size, void* d_ws, size_t ws_size,
                              hipStream_t stream) {
    const float* query = (const float*)d_in[0];
    const float* key_  = (const float*)d_in[1];
    const float* value = (const float*)d_in[2];
    const float* Wq = (const float*)d_in[3];
    const float* bq = (const float*)d_in[4];
    const float* Wk = (const float*)d_in[5];
    const float* bk = (const float*)d_in[6];
    const float* Wv = (const float*)d_in[7];
    const float* bv = (const float*)d_in[8];
    const float* Wm = (const float*)d_in[9];
    const float* bm = (const float*)d_in[10];

    char* w = (char*)d_ws;
    f16*   w16    = (f16*)w;                        // 524288 B
    float* bperm  = (float*)(w + 524288);           // 3072 B
    float* KVpart = (float*)(w + 528384);           // 16*64*1024*4 = 4194304 B
    float* ksum_p = (float*)(w + 4722688);          // 16*64*32*4 = 131072 B
    float* KVfin  = (float*)(w + 4853760);          // 262144 B
    float* ksum_f = (float*)(w + 5115904);          // 8192 B
    f16*   qp     = (f16*)(w + 5124096);            // 16.7 MB each
    f16*   kp     = qp + (size_t)BATCH * SEQL * 256;
    f16*   vp     = kp + (size_t)BATCH * SEQL * 256;

    prep_kernel<<<1025, 256, 0, stream>>>(Wq, Wk, Wv, Wm, bq, bk, bv, w16, bperm);

    gemm_stage1<<<dim3(SEQL / 64, 1, 24), 256, 0, stream>>>(
        query, key_, value, w16, bperm, qp, kp, vp);

    kv_mfma<<<dim3(NSPLIT, BATCH * NHEADS), 256, 0, stream>>>(kp, vp, KVpart, ksum_p);

    kv_reduce<<<dim3(BATCH * NHEADS), 256, 0, stream>>>(KVpart, ksum_p, KVfin, ksum_f);

    attn_out_kernel<<<dim3(SEQL / 64, BATCH), 256, 0, stream>>>(
        qp, KVfin, ksum_f, w16 + 3 * 65536, bm, (float*)d_out);
}